// Round 4
// baseline (5445.905 us; speedup 1.0000x reference)
//
#include <hip/hip_runtime.h>
#include <hip/hip_bf16.h>

// ---------------------------------------------------------------------------
// CFODE: bi-GRU encoder/decoder -> latent SDE (140 Euler steps, 3-layer MLP
// drift with tanh+LayerNorm) -> decoder head.
//
// Round 4:
//  * Revert to round-2 flag-barrier exchange (bulk L2-served reads). Tag-poll
//    (round 3) caused 3.1 GB of poll refetch traffic — removed.
//  * k_sde: 512 WGs = 32 rowgs x 4 rows x 16 colg, __launch_bounds__(256,2)
//    -> 2 WGs/CU, paired WGs are different cohorts (latency overlap).
//  * Exchange ops halved: adjacent col pair packed in one u64; LN partials
//    {s1,s2} packed in one u64.
//  * GRU: enc+dec merged into one 512-block launch; direct uint4 weight loads.
// ---------------------------------------------------------------------------

#define EPS    1e-5f
#define DT_    0.05f
#define SQDT_  0.22360680997371674f   // sqrt(0.05)
#define SIG_   0.5f

#define NB    128
#define NLH   64
#define NLP   8
#define NSTEP 140
#define NSUB  20

// ws layout (float offsets). Total ~507K floats (~2.0 MB).
#define WSH_OFF   0           // [128 rows][4 which][128]      = 65536
#define YS_OFF    65536       // [128 rows][8 samples][257]    = 263168
#define ACTA_OFF  328704      // [32 rowg][1024 u64]           = 65536 fl
#define ACTB_OFF  394240      // [32 rowg][1024 u64]           = 65536 fl
#define ACTC_OFF  459776      // [32 rowg][512 u64]            = 32768 fl
#define PSA_OFF   492544      // [32 rowg][64 u64]             = 4096 fl
#define PSB_OFF   496640
#define PSC_OFF   500736
#define SLOT_OFF  504832      // 8192 u32 barrier slots        = 2048 fl

typedef unsigned long long u64t;
union U64 { u64t u; float f[2]; unsigned w[2]; };

__device__ __forceinline__ float bf2f(unsigned short u) {
  return __uint_as_float(((unsigned)u) << 16);
}
__device__ __forceinline__ void up2(unsigned u, float* d) {
  d[0] = bf2f((unsigned short)(u & 0xffff));
  d[1] = bf2f((unsigned short)(u >> 16));
}
__device__ __forceinline__ float ldv(const void* p, int i, bool bf) {
  return bf ? bf2f(((const unsigned short*)p)[i]) : ((const float*)p)[i];
}
__device__ __forceinline__ void st_out(void* p, int i, float v, bool bf) {
  if (bf) ((__hip_bfloat16*)p)[i] = __float2bfloat16(v);
  else    ((float*)p)[i] = v;
}
__device__ __forceinline__ float sigm(float x) { return 1.f / (1.f + expf(-x)); }

// Relaxed agent-scope 64-bit exchange (L2-point-coherent intra-XCD, no
// cache-maintenance fences).
__device__ __forceinline__ void g_st64(u64t* p, u64t v) {
  __hip_atomic_store(p, v, __ATOMIC_RELAXED, __HIP_MEMORY_SCOPE_AGENT);
}
__device__ __forceinline__ u64t g_ld64(const u64t* p) {
  return __hip_atomic_load(p, __ATOMIC_RELAXED, __HIP_MEMORY_SCOPE_AGENT);
}
__device__ __forceinline__ u64t pk2(float a, float b) {
  U64 t; t.f[0] = a; t.f[1] = b; return t.u;
}

// ---------------------------------------------------------------------------
// GRU: 384 threads, thread j owns gate-row j (0..127 r, 128..255 z, 256..383 n)
// ---------------------------------------------------------------------------
template<int INSZ, int TSTEPS>
__device__ void gru_run(const float* xs, int rev,
                        const void* Wih, const void* Whh,
                        const void* bih, const void* bhh,
                        bool bf, float* hout,
                        float* h0, float* h1, float* rz)
{
  const int j = threadIdx.x;
  float whh[128];
  float wih[INSZ];
  if (bf) {
    const unsigned short* wp = (const unsigned short*)Whh;  // row j: 256B aligned
    #pragma unroll
    for (int k8 = 0; k8 < 16; ++k8) {
      const uint4 q = *(const uint4*)&wp[j*128 + k8*8];
      up2(q.x, &whh[k8*8+0]); up2(q.y, &whh[k8*8+2]);
      up2(q.z, &whh[k8*8+4]); up2(q.w, &whh[k8*8+6]);
    }
    const unsigned short* ip = (const unsigned short*)Wih;
    #pragma unroll
    for (int c2 = 0; c2 < INSZ/2; ++c2) {   // 4B-aligned pairs
      const unsigned u = *(const unsigned*)&ip[j*INSZ + c2*2];
      up2(u, &wih[c2*2]);
    }
  } else {
    const float* wp = (const float*)Whh;
    #pragma unroll
    for (int k4 = 0; k4 < 32; ++k4) {
      const float4 q = *(const float4*)&wp[j*128 + k4*4];
      whh[k4*4+0]=q.x; whh[k4*4+1]=q.y; whh[k4*4+2]=q.z; whh[k4*4+3]=q.w;
    }
    const float* ip = (const float*)Wih;
    #pragma unroll
    for (int c = 0; c < INSZ; ++c) wih[c] = ip[j*INSZ + c];
  }
  const float bi = ldv(bih, j, bf);
  const float bh = ldv(bhh, j, bf);
  if (j < 128) h0[j] = 0.f;
  __syncthreads();

  #pragma unroll 1
  for (int it = 0; it < TSTEPS; ++it) {
    const float* hc = (it & 1) ? h1 : h0;
    float*       hn = (it & 1) ? h0 : h1;
    const int t = rev ? (TSTEPS - 1 - it) : it;
    float gh = bh;
    const float4* h4 = (const float4*)hc;
    #pragma unroll
    for (int k4 = 0; k4 < 32; ++k4) {
      const float4 hv = h4[k4];
      gh += whh[k4*4+0]*hv.x + whh[k4*4+1]*hv.y + whh[k4*4+2]*hv.z + whh[k4*4+3]*hv.w;
    }
    float gi = bi;
    #pragma unroll
    for (int c = 0; c < INSZ; ++c) gi += wih[c] * xs[t*INSZ + c];
    if (j < 256) rz[j] = sigm(gi + gh);      // r (0..127), z (128..255)
    __syncthreads();
    if (j >= 256) {                           // n-threads also do the h update
      const int i = j - 256;
      const float n = tanhf(gi + rz[i]*gh);   // inn + r*hn (biases kept separate)
      const float z = rz[128 + i];
      hn[i] = (1.f - z)*n + z*hc[i];
    }
    __syncthreads();
  }
  const float* hf = (TSTEPS & 1) ? h1 : h0;
  if (j < 128) hout[j] = hf[j];
}

// Merged encoder+decoder GRU: blocks 0..255 = enc (row, dir), 256..511 = dec.
__global__ __launch_bounds__(384)
void k_gru(const void* cov, const void* trh, const void* outh, const void* trt,
           const void* eWf, const void* eUf, const void* ebf, const void* ecf,
           const void* eWb, const void* eUb, const void* ebb, const void* ecb,
           const void* dWf, const void* dUf, const void* dbf, const void* dcf,
           const void* dWb, const void* dUb, const void* dbb, const void* dcb,
           float* ws, const void* lnvw)
{
  __shared__ __align__(16) float xs[NLH*28];
  __shared__ __align__(16) float h0[128], h1[128];
  __shared__ float rz[256];
  __shared__ float sm_[28], ss_[28];
  const bool bf = (((const unsigned*)lnvw)[0] != 0x3F800000u);
  const int bid = blockIdx.x;
  const int tid = threadIdx.x;

  if (bid == 0) {  // zero SDE barrier slots (ws re-poisoned before every call)
    unsigned* slots = (unsigned*)(ws + SLOT_OFF);
    for (int e = tid; e < 8192; e += 384) slots[e] = 0u;
  }

  if (bid < 256) {  // ---- encoder ----
    const int row = bid >> 1, back = bid & 1;
    if (tid < 28) {  // per-feature mean/std over time (population std)
      const void* src; int w; int f2;
      if (tid < 16)      { src = cov;  w = 16; f2 = tid; }
      else if (tid < 24) { src = trh;  w = 8;  f2 = tid - 16; }
      else               { src = outh; w = 4;  f2 = tid - 24; }
      float s1 = 0.f, s2 = 0.f;
      for (int t = 0; t < NLH; ++t) {
        const float v = ldv(src, (row*NLH + t)*w + f2, bf);
        s1 += v; s2 += v*v;
      }
      const float m = s1 / NLH;
      const float var = s2 / NLH - m*m;
      sm_[tid] = m;
      ss_[tid] = sqrtf(fmaxf(var, 0.f)) + EPS;
    }
    __syncthreads();
    for (int e = tid; e < NLH*28; e += 384) {  // enc_in = [ch(16), th(8), oh(4)]
      const int t = e / 28, f2 = e % 28;
      const void* src; int w; int ff;
      if (f2 < 16)      { src = cov;  w = 16; ff = f2; }
      else if (f2 < 24) { src = trh;  w = 8;  ff = f2 - 16; }
      else              { src = outh; w = 4;  ff = f2 - 24; }
      const float v = ldv(src, (row*NLH + t)*w + ff, bf);
      xs[e] = (v - sm_[f2]) / ss_[f2];
    }
    __syncthreads();
    float* hout = ws + WSH_OFF + (row*4 + back)*128;
    if (back == 0) gru_run<28, NLH>(xs, 0, eWf, eUf, ebf, ecf, bf, hout, h0, h1, rz);
    else           gru_run<28, NLH>(xs, 1, eWb, eUb, ebb, ecb, bf, hout, h0, h1, rz);
  } else {          // ---- decoder ----
    const int b2 = bid - 256;
    const int row = b2 >> 1, back = b2 & 1;
    if (tid < 8) {  // treatment stats come from treatment_history
      float s1 = 0.f, s2 = 0.f;
      for (int t = 0; t < NLH; ++t) {
        const float v = ldv(trh, (row*NLH + t)*8 + tid, bf);
        s1 += v; s2 += v*v;
      }
      const float m = s1 / NLH;
      const float var = s2 / NLH - m*m;
      sm_[tid] = m;
      ss_[tid] = sqrtf(fmaxf(var, 0.f)) + EPS;
    }
    __syncthreads();
    for (int e = tid; e < NLP*8; e += 384) {
      const int t = e >> 3, f2 = e & 7;
      const float v = ldv(trt, (row*NLP + t)*8 + f2, bf);
      xs[e] = (v - sm_[f2]) / ss_[f2];
    }
    __syncthreads();
    float* hout = ws + WSH_OFF + (row*4 + 2 + back)*128;
    if (back == 0) gru_run<8, NLP>(xs, 0, dWf, dUf, dbf, dcf, bf, hout, h0, h1, rz);
    else           gru_run<8, NLP>(xs, 1, dWb, dUb, dbb, dcb, bf, hout, h0, h1, rz);
  }
}

// ---------------------------------------------------------------------------
// SDE kernel: 512 WGs = 32 rowgs (4 batch rows) x 16 colgs, 2 WGs/CU.
// ---------------------------------------------------------------------------
__device__ __forceinline__ void cohort_bar(unsigned* slots, int rowg, int colg,
                                           unsigned phase)
{
  asm volatile("s_waitcnt vmcnt(0)" ::: "memory");  // own data stores drained
  __syncthreads();                                  // all waves drained
  if (threadIdx.x == 0)
    __hip_atomic_store(&slots[(rowg*16 + colg)*16], phase,
                       __ATOMIC_RELAXED, __HIP_MEMORY_SCOPE_AGENT);
  if (threadIdx.x < 16) {
    const unsigned* p = &slots[(rowg*16 + (int)threadIdx.x)*16];
    while (__hip_atomic_load(p, __ATOMIC_RELAXED, __HIP_MEMORY_SCOPE_AGENT) < phase) { }
  }
  asm volatile("s_waitcnt vmcnt(0)" ::: "memory");  // poll loads complete
  __syncthreads();
}

// One layer for 4 rows: this WG computes NC output cols (2 cols x KSPLIT
// k-chunks per thread, weights in regs); writes packed col-pair u64s + packed
// LN partials.
template<int K, int NC, int KSPLIT, int KPC>
__device__ __forceinline__ void mlp_layer(
    const float* in,          // LDS, 4 rows, stride K
    const float* w,           // per-thread regs: 2 cols x KPC
    const float* biasL,       // LDS full-layer bias
    float* scr, float* tsl,
    u64t* actG, u64t* psG,    // global u64 views, rowg-offset bases
    int colg)
{
  const int tid = threadIdx.x;
  const int cp = tid % (NC/2);
  const int kc = tid / (NC/2);
  const int kk = kc * KPC;
  float p0[4], p1[4];
  #pragma unroll
  for (int r = 0; r < 4; ++r) { p0[r] = 0.f; p1[r] = 0.f; }
  #pragma unroll
  for (int i = 0; i < KPC; i += 4) {
    const float wa0 = w[i],     wa1 = w[i+1],     wa2 = w[i+2],     wa3 = w[i+3];
    const float wb0 = w[KPC+i], wb1 = w[KPC+i+1], wb2 = w[KPC+i+2], wb3 = w[KPC+i+3];
    #pragma unroll
    for (int r = 0; r < 4; ++r) {
      const float4 av = *(const float4*)(in + r*K + kk + i);
      p0[r] += wa0*av.x + wa1*av.y + wa2*av.z + wa3*av.w;
      p1[r] += wb0*av.x + wb1*av.y + wb2*av.z + wb3*av.w;
    }
  }
  #pragma unroll
  for (int r = 0; r < 4; ++r) {            // stride-5 pad reduce scratch
    scr[(kc*NC + 2*cp + 0)*5 + r] = p0[r];
    scr[(kc*NC + 2*cp + 1)*5 + r] = p1[r];
  }
  __syncthreads();
  if (tid < 4*(NC/2)) {                    // one row, 2 adjacent cols / thread
    const int r = tid / (NC/2), c2 = tid % (NC/2);
    float v0 = biasL[colg*NC + 2*c2 + 0];
    float v1 = biasL[colg*NC + 2*c2 + 1];
    #pragma unroll
    for (int q = 0; q < KSPLIT; ++q) {
      v0 += scr[(q*NC + 2*c2 + 0)*5 + r];
      v1 += scr[(q*NC + 2*c2 + 1)*5 + r];
    }
    const float t0 = tanhf(v0), t1 = tanhf(v1);
    tsl[r*NC + 2*c2 + 0] = t0;
    tsl[r*NC + 2*c2 + 1] = t1;
    g_st64(&actG[r*(NC*8) + colg*(NC/2) + c2], pk2(t0, t1));
  }
  __syncthreads();
  if (tid < 4) {                            // packed LN partials for this slice
    float s1 = 0.f, s2 = 0.f;
    #pragma unroll
    for (int cl = 0; cl < NC; ++cl) { const float v = tsl[tid*NC + cl]; s1 += v; s2 += v*v; }
    g_st64(&psG[colg*4 + tid], pk2(s1, s2));
  }
}

// After the cohort barrier: bulk-read activation + partials, finish LN,
// apply *g+be in place in LDS.
template<int NCT>
__device__ __forceinline__ void consume(
    float* act, const u64t* actG, const u64t* psG,
    const float* gL, const float* beL,
    float* psL, float* mrow, float* rsrow)
{
  const int tid = threadIdx.x;
  for (int e = tid; e < (4*NCT)/2; e += 256) {
    U64 t; t.u = g_ld64(actG + e);
    act[2*e + 0] = t.f[0];
    act[2*e + 1] = t.f[1];
  }
  if (tid < 64) {
    U64 t; t.u = g_ld64(psG + tid);
    psL[2*tid + 0] = t.f[0];
    psL[2*tid + 1] = t.f[1];
  }
  __syncthreads();
  if (tid < 4) {
    float s1 = 0.f, s2 = 0.f;
    #pragma unroll
    for (int cg = 0; cg < 16; ++cg) {
      s1 += psL[(cg*4 + tid)*2 + 0];
      s2 += psL[(cg*4 + tid)*2 + 1];
    }
    const float m = s1 / (float)NCT;
    const float var = s2 / (float)NCT - m*m;
    mrow[tid] = m;
    rsrow[tid] = rsqrtf(var + EPS);
  }
  __syncthreads();
  for (int e = tid; e < 4*NCT; e += 256) {
    const int r = e / NCT, k2 = e % NCT;
    act[e] = (act[e] - mrow[r])*rsrow[r]*gL[k2] + beL[k2];
  }
  __syncthreads();
}

__global__ __launch_bounds__(256, 2)
void k_sde(float* ws,
           const void* W0, const void* b0, const void* g0, const void* be0,
           const void* W1, const void* b1, const void* g1, const void* be1,
           const void* W2, const void* b2, const void* g2, const void* be2,
           const void* noise, const void* lnvw)
{
  __shared__ __align__(16) float st[4*256];
  __shared__ __align__(16) float act[4*512];
  __shared__ __align__(16) float scr[2560];
  __shared__ float gA[512], beA[512], gB[512], beB[512], gC[256], beC[256];
  __shared__ float bA[512], bB[512], bC[256];
  __shared__ float psL[128], tsl[128];
  __shared__ float mrow[4], rsrow[4], lacc[4];

  const bool bf = (((const unsigned*)lnvw)[0] != 0x3F800000u);
  const int tid  = threadIdx.x;
  const int bid  = blockIdx.x;
  // Cohort members (same rowg) share bid%8 -> same XCD under round-robin;
  // co-resident CU pair (bid, bid+256) = different rowgs -> latency overlap.
  const int rowg = ((bid >> 8) << 4) | (bid & 15);
  const int colg = (bid >> 4) & 15;

  for (int e = tid; e < 512; e += 256) {
    gA[e] = ldv(g0, e, bf); beA[e] = ldv(be0, e, bf);
    gB[e] = ldv(g1, e, bf); beB[e] = ldv(be1, e, bf);
    bA[e] = ldv(b0, e, bf); bB[e] = ldv(b1, e, bf);
  }
  gC[tid] = ldv(g2, tid, bf); beC[tid] = ldv(be2, tid, bf);
  bC[tid] = ldv(b2, tid, bf);

  // Per-thread weight slice in registers for the whole kernel.
  float w0[32], w1[64], w2[32];
  {
    const int cp = tid % 16, kc = tid / 16;
    #pragma unroll
    for (int cc = 0; cc < 2; ++cc)
      #pragma unroll
      for (int i = 0; i < 16; ++i)
        w0[cc*16 + i] = ldv(W0, (colg*32 + 2*cp + cc)*256 + kc*16 + i, bf);
    #pragma unroll
    for (int cc = 0; cc < 2; ++cc)
      #pragma unroll
      for (int i = 0; i < 32; ++i)
        w1[cc*32 + i] = ldv(W1, (colg*32 + 2*cp + cc)*512 + kc*32 + i, bf);
    const int cp2 = tid % 8, kc2 = tid / 8;
    #pragma unroll
    for (int cc = 0; cc < 2; ++cc)
      #pragma unroll
      for (int i = 0; i < 16; ++i)
        w2[cc*16 + i] = ldv(W2, (colg*16 + 2*cp2 + cc)*512 + kc2*16 + i, bf);
  }

  // x0 = [0.5*(enc_f+enc_b), 0.5*(dec_f+dec_b)] for this WG's 4 rows.
  const float* wsh = ws + WSH_OFF;
  for (int e = tid; e < 4*256; e += 256) {
    const int r = e >> 8, d = e & 255;
    const int row = rowg*4 + r;
    float v;
    if (d < 128) v = 0.5f*(wsh[(row*4 + 0)*128 + d]         + wsh[(row*4 + 1)*128 + d]);
    else         v = 0.5f*(wsh[(row*4 + 2)*128 + (d - 128)] + wsh[(row*4 + 3)*128 + (d - 128)]);
    st[e] = v;
  }
  if (tid < 4) lacc[tid] = 0.f;
  __syncthreads();
  float* ysw = ws + YS_OFF;
  if (colg == 0) {  // sample 0 = aug0
    for (int e = tid; e < 4*257; e += 256) {
      const int r = e / 257, d = e % 257;
      ysw[((rowg*4 + r)*8 + 0)*257 + d] = (d < 256) ? st[r*256 + d] : 0.f;
    }
  }

  u64t* actAg = (u64t*)(ws + ACTA_OFF) + rowg*1024;
  u64t* actBg = (u64t*)(ws + ACTB_OFF) + rowg*1024;
  u64t* actCg = (u64t*)(ws + ACTC_OFF) + rowg*512;
  u64t* psAg  = (u64t*)(ws + PSA_OFF)  + rowg*64;
  u64t* psBg  = (u64t*)(ws + PSB_OFF)  + rowg*64;
  u64t* psCg  = (u64t*)(ws + PSC_OFF)  + rowg*64;
  unsigned* slots = (unsigned*)(ws + SLOT_OFF);

  unsigned phase = 1;
  #pragma unroll 1
  for (int s = 0; s < NSTEP; ++s) {
    // Prefetch this step's noise into regs (consumed after layer C).
    const int r = tid >> 5, d0 = (tid & 31)*8;
    const int nb = ((s*NB) + rowg*4 + r)*256 + d0;
    uint4 nzb; float4 nf0, nf1;
    if (tid < 128) {
      if (bf) nzb = *(const uint4*)((const unsigned short*)noise + nb);
      else { nf0 = *(const float4*)((const float*)noise + nb);
             nf1 = *(const float4*)((const float*)noise + nb + 4); }
    }

    mlp_layer<256, 32, 16, 16>(st,  w0, bA, scr, tsl, actAg, psAg, colg);
    cohort_bar(slots, rowg, colg, phase); ++phase;
    consume<512>(act, actAg, psAg, gA, beA, psL, mrow, rsrow);

    mlp_layer<512, 32, 16, 32>(act, w1, bB, scr, tsl, actBg, psBg, colg);
    cohort_bar(slots, rowg, colg, phase); ++phase;
    consume<512>(act, actBg, psBg, gB, beB, psL, mrow, rsrow);

    mlp_layer<512, 16, 32, 16>(act, w2, bC, scr, tsl, actCg, psCg, colg);
    cohort_bar(slots, rowg, colg, phase); ++phase;
    consume<256>(act, actCg, psCg, gC, beC, psL, mrow, rsrow);

    // Euler step + flq, replicated (bitwise identical) in every cohort WG.
    if (tid < 128) {
      float nz[8];
      if (bf) { up2(nzb.x,&nz[0]); up2(nzb.y,&nz[2]); up2(nzb.z,&nz[4]); up2(nzb.w,&nz[6]); }
      else { nz[0]=nf0.x; nz[1]=nf0.y; nz[2]=nf0.z; nz[3]=nf0.w;
             nz[4]=nf1.x; nz[5]=nf1.y; nz[6]=nf1.z; nz[7]=nf1.w; }
      float u2 = 0.f;
      #pragma unroll
      for (int q = 0; q < 8; ++q) {
        const float ys = st[r*256 + d0 + q];
        const float f  = act[r*256 + d0 + q];
        const float uu = f + ys;                 // u = 2*(f+ys); scale later
        u2 += uu*uu;
        st[r*256 + d0 + q] = ys + f*DT_ + SIG_*SQDT_*nz[q];
      }
      scr[tid] = u2;
    }
    __syncthreads();
    if (tid < 4) {
      float tot = 0.f;
      #pragma unroll
      for (int c = 0; c < 32; ++c) tot += scr[tid*32 + c];
      lacc[tid] += 2.f*tot*DT_;                  // flq*DT = 0.5*sum((2u)^2)*DT
    }
    __syncthreads();
    if (((s + 1) % NSUB) == 0 && colg == 0) {
      const int smp = (s + 1)/NSUB;
      for (int e = tid; e < 4*257; e += 256) {
        const int rr = e / 257, d = e % 257;
        ysw[((rowg*4 + rr)*8 + smp)*257 + d] = (d < 256) ? st[rr*256 + d] : lacc[rr];
      }
    }
    __syncthreads();
  }
}

// ---------------------------------------------------------------------------
// Epilogue: decoder head + output packing (mu | var | logqp)
// ---------------------------------------------------------------------------
__global__ __launch_bounds__(128)
void k_epi(const float* ws, const void* outh,
           const void* outW, const void* outB,
           const void* lvw, const void* lvb,
           void* d_out)
{
  __shared__ __align__(16) float ysl[8*257];
  __shared__ __align__(16) float ow[8*128];
  __shared__ float dout[64];
  __shared__ float om4[4], os4[4], vmv[4], vrs[4], ob[8], lw[4], lb[4];
  const bool bf = (((const unsigned*)lvw)[0] != 0x3F800000u);
  const int row = blockIdx.x, tid = threadIdx.x;
  const float* ysw = ws + YS_OFF + row*(8*257);
  for (int e = tid; e < 8*257; e += 128) ysl[e] = ysw[e];
  for (int e = tid; e < 1024; e += 128)  ow[e]  = ldv(outW, e, bf);
  if (tid < 8) ob[tid] = ldv(outB, tid, bf);
  if (tid < 4) { lw[tid] = ldv(lvw, tid, bf); lb[tid] = ldv(lvb, tid, bf); }
  if (tid < 4) {  // om / os_ from outcome_history
    float s1 = 0.f, s2 = 0.f;
    for (int t = 0; t < NLH; ++t) {
      const float v = ldv(outh, (row*NLH + t)*4 + tid, bf);
      s1 += v; s2 += v*v;
    }
    const float m = s1 / NLH;
    const float var = s2 / NLH - m*m;
    om4[tid] = m;
    os4[tid] = sqrtf(fmaxf(var, 0.f)) + EPS;   // already includes +EPS
  }
  __syncthreads();
  if (tid < 64) {
    const int smp = tid >> 3, o = tid & 7;
    float a = ob[o];
    #pragma unroll
    for (int k = 0; k < 128; ++k) a += ysl[smp*257 + k]*ow[o*128 + k];
    dout[smp*8 + o] = a;
  }
  __syncthreads();
  if (tid < 4) {  // var_o mean/var over the 8 samples
    float s1 = 0.f, s2 = 0.f;
    #pragma unroll
    for (int smp = 0; smp < 8; ++smp) { const float v = dout[smp*8 + 4 + tid]; s1 += v; s2 += v*v; }
    const float m = s1 / 8.f;
    const float var = s2 / 8.f - m*m;
    vmv[tid] = m;
    vrs[tid] = rsqrtf(var + EPS);
  }
  __syncthreads();
  if (tid < 32) {
    const int smp = tid >> 2, j = tid & 3;
    const float mu = dout[smp*8 + j]*os4[j] + om4[j];
    st_out(d_out, (row*8 + smp)*4 + j, mu, bf);
    const float vo = dout[smp*8 + 4 + j];
    const float vr = sigm((vo - vmv[j])*vrs[j]*lw[j] + lb[j]);
    st_out(d_out, 4096 + (row*8 + smp)*4 + j, vr, bf);
  }
  for (int e = tid; e < 129*8; e += 128) {
    const int j = e >> 3, smp = e & 7;
    st_out(d_out, 8192 + (row*129 + j)*8 + smp, ysl[smp*257 + 128 + j], bf);
  }
}

// ---------------------------------------------------------------------------
extern "C" void kernel_launch(void* const* d_in, const int* in_sizes, int n_in,
                              void* d_out, int out_size, void* d_ws, size_t ws_size,
                              hipStream_t stream) {
  (void)in_sizes; (void)n_in; (void)out_size; (void)ws_size;
  float* ws = (float*)d_ws;
  const void* lnvw = d_in[35];

  k_gru<<<512, 384, 0, stream>>>(
      d_in[0], d_in[1], d_in[2], d_in[3],
      d_in[5], d_in[6], d_in[7], d_in[8],
      d_in[9], d_in[10], d_in[11], d_in[12],
      d_in[13], d_in[14], d_in[15], d_in[16],
      d_in[17], d_in[18], d_in[19], d_in[20],
      ws, lnvw);
  k_sde<<<512, 256, 0, stream>>>(
      ws,
      d_in[21], d_in[22], d_in[23], d_in[24],
      d_in[25], d_in[26], d_in[27], d_in[28],
      d_in[29], d_in[30], d_in[31], d_in[32],
      d_in[37], lnvw);
  k_epi<<<128, 128, 0, stream>>>(
      (const float*)d_ws, d_in[2],
      d_in[33], d_in[34], d_in[35], d_in[36],
      d_out);
}

// Round 5
// 4000.765 us; speedup vs baseline: 1.3612x; 1.3612x over previous
//
#include <hip/hip_runtime.h>
#include <hip/hip_bf16.h>

// ---------------------------------------------------------------------------
// CFODE: bi-GRU encoder/decoder -> latent SDE (140 Euler steps, 3-layer MLP
// drift with tanh+LayerNorm) -> decoder head.
//
// Round 5:
//  * Back to 256-WG topology (16 rowg-pairs x 16 colg, 1 WG/CU).
//  * Intra-WG two-half pipelining: 8 rows = 2 x 4-row halves with separate
//    exchange buffers + counters; every cohort WAIT is preceded by the other
//    half's layer compute (latency hiding without co-residency).
//  * Counter barrier: one atomicAdd per WG arrival, single polling lane with
//    s_sleep backoff (kills round-4's poll-fetch storm).
//  * LN affine folded into weights: W1*=g0, W2*=g1 (+ per-col Sum(w*g),
//    Sum(w*be) constants); layer-2 g/be applied inline in the Euler update.
//    Removes all per-step normalize passes.
// ---------------------------------------------------------------------------

#define EPS    1e-5f
#define DT_    0.05f
#define SQDT_  0.22360680997371674f   // sqrt(0.05)
#define SIG_   0.5f

#define NB    128
#define NLH   64
#define NLP   8
#define NSTEP 140
#define NSUB  20

// ws layout (float offsets). Total ~505K floats (~2.0 MB).
#define WSH_OFF   0           // [128 rows][4 which][128]      = 65536
#define YS_OFF    65536       // [128 rows][8 samples][257]    = 263168
#define ACTA_OFF  328704      // [32 rowg][1024 u64]           = 65536 fl
#define ACTB_OFF  394240      // [32 rowg][1024 u64]           = 65536 fl
#define ACTC_OFF  459776      // [32 rowg][512 u64]            = 32768 fl
#define PSA_OFF   492544      // [32 rowg][64 u64]             = 4096 fl
#define PSB_OFF   496640
#define PSC_OFF   500736
#define CNT_OFF   504832      // [32 rowg][3 layers][16 u32]   = 1536 u32

typedef unsigned long long u64t;
union U64 { u64t u; float f[2]; unsigned w[2]; };

__device__ __forceinline__ float bf2f(unsigned short u) {
  return __uint_as_float(((unsigned)u) << 16);
}
__device__ __forceinline__ void up2(unsigned u, float* d) {
  d[0] = bf2f((unsigned short)(u & 0xffff));
  d[1] = bf2f((unsigned short)(u >> 16));
}
__device__ __forceinline__ float ldv(const void* p, int i, bool bf) {
  return bf ? bf2f(((const unsigned short*)p)[i]) : ((const float*)p)[i];
}
__device__ __forceinline__ void st_out(void* p, int i, float v, bool bf) {
  if (bf) ((__hip_bfloat16*)p)[i] = __float2bfloat16(v);
  else    ((float*)p)[i] = v;
}
__device__ __forceinline__ float sigm(float x) { return 1.f / (1.f + expf(-x)); }

// Relaxed agent-scope 64-bit exchange (bypasses L1; L2/coherence-point served).
__device__ __forceinline__ void g_st64(u64t* p, u64t v) {
  __hip_atomic_store(p, v, __ATOMIC_RELAXED, __HIP_MEMORY_SCOPE_AGENT);
}
__device__ __forceinline__ u64t g_ld64(const u64t* p) {
  return __hip_atomic_load(p, __ATOMIC_RELAXED, __HIP_MEMORY_SCOPE_AGENT);
}
__device__ __forceinline__ u64t pk2(float a, float b) {
  U64 t; t.f[0] = a; t.f[1] = b; return t.u;
}

// Arrival: drain own stores (all waves), then one atomicAdd.
__device__ __forceinline__ void bar_arrive(unsigned* c) {
  asm volatile("s_waitcnt vmcnt(0)" ::: "memory");
  __syncthreads();
  if (threadIdx.x == 0)
    __hip_atomic_fetch_add(c, 1u, __ATOMIC_RELAXED, __HIP_MEMORY_SCOPE_AGENT);
}
// Wait: single lane polls with sleep backoff, then joins the WG.
__device__ __forceinline__ void bar_wait(const unsigned* c, unsigned tgt) {
  if (threadIdx.x == 0) {
    while (__hip_atomic_load(c, __ATOMIC_RELAXED, __HIP_MEMORY_SCOPE_AGENT) < tgt)
      __builtin_amdgcn_s_sleep(1);
  }
  __syncthreads();
}

// ---------------------------------------------------------------------------
// GRU: 384 threads, thread j owns gate-row j (0..127 r, 128..255 z, 256..383 n)
// ---------------------------------------------------------------------------
template<int INSZ, int TSTEPS>
__device__ void gru_run(const float* xs, int rev,
                        const void* Wih, const void* Whh,
                        const void* bih, const void* bhh,
                        bool bf, float* hout,
                        float* h0, float* h1, float* rz)
{
  const int j = threadIdx.x;
  float whh[128];
  float wih[INSZ];
  if (bf) {
    const unsigned short* wp = (const unsigned short*)Whh;  // row j: 256B aligned
    #pragma unroll
    for (int k8 = 0; k8 < 16; ++k8) {
      const uint4 q = *(const uint4*)&wp[j*128 + k8*8];
      up2(q.x, &whh[k8*8+0]); up2(q.y, &whh[k8*8+2]);
      up2(q.z, &whh[k8*8+4]); up2(q.w, &whh[k8*8+6]);
    }
    const unsigned short* ip = (const unsigned short*)Wih;
    #pragma unroll
    for (int c2 = 0; c2 < INSZ/2; ++c2) {   // 4B-aligned pairs
      const unsigned u = *(const unsigned*)&ip[j*INSZ + c2*2];
      up2(u, &wih[c2*2]);
    }
  } else {
    const float* wp = (const float*)Whh;
    #pragma unroll
    for (int k4 = 0; k4 < 32; ++k4) {
      const float4 q = *(const float4*)&wp[j*128 + k4*4];
      whh[k4*4+0]=q.x; whh[k4*4+1]=q.y; whh[k4*4+2]=q.z; whh[k4*4+3]=q.w;
    }
    const float* ip = (const float*)Wih;
    #pragma unroll
    for (int c = 0; c < INSZ; ++c) wih[c] = ip[j*INSZ + c];
  }
  const float bi = ldv(bih, j, bf);
  const float bh = ldv(bhh, j, bf);
  if (j < 128) h0[j] = 0.f;
  __syncthreads();

  #pragma unroll 1
  for (int it = 0; it < TSTEPS; ++it) {
    const float* hc = (it & 1) ? h1 : h0;
    float*       hn = (it & 1) ? h0 : h1;
    const int t = rev ? (TSTEPS - 1 - it) : it;
    float gh = bh;
    const float4* h4 = (const float4*)hc;
    #pragma unroll
    for (int k4 = 0; k4 < 32; ++k4) {
      const float4 hv = h4[k4];
      gh += whh[k4*4+0]*hv.x + whh[k4*4+1]*hv.y + whh[k4*4+2]*hv.z + whh[k4*4+3]*hv.w;
    }
    float gi = bi;
    #pragma unroll
    for (int c = 0; c < INSZ; ++c) gi += wih[c] * xs[t*INSZ + c];
    if (j < 256) rz[j] = sigm(gi + gh);      // r (0..127), z (128..255)
    __syncthreads();
    if (j >= 256) {                           // n-threads also do the h update
      const int i = j - 256;
      const float n = tanhf(gi + rz[i]*gh);   // inn + r*hn (biases kept separate)
      const float z = rz[128 + i];
      hn[i] = (1.f - z)*n + z*hc[i];
    }
    __syncthreads();
  }
  const float* hf = (TSTEPS & 1) ? h1 : h0;
  if (j < 128) hout[j] = hf[j];
}

// Merged encoder+decoder GRU: blocks 0..255 = enc (row, dir), 256..511 = dec.
__global__ __launch_bounds__(384)
void k_gru(const void* cov, const void* trh, const void* outh, const void* trt,
           const void* eWf, const void* eUf, const void* ebf, const void* ecf,
           const void* eWb, const void* eUb, const void* ebb, const void* ecb,
           const void* dWf, const void* dUf, const void* dbf, const void* dcf,
           const void* dWb, const void* dUb, const void* dbb, const void* dcb,
           float* ws, const void* lnvw)
{
  __shared__ __align__(16) float xs[NLH*28];
  __shared__ __align__(16) float h0[128], h1[128];
  __shared__ float rz[256];
  __shared__ float sm_[28], ss_[28];
  const bool bf = (((const unsigned*)lnvw)[0] != 0x3F800000u);
  const int bid = blockIdx.x;
  const int tid = threadIdx.x;

  if (bid == 0) {  // zero SDE barrier counters (ws re-poisoned every call)
    unsigned* cnt = (unsigned*)(ws + CNT_OFF);
    for (int e = tid; e < 1536; e += 384) cnt[e] = 0u;
  }

  if (bid < 256) {  // ---- encoder ----
    const int row = bid >> 1, back = bid & 1;
    if (tid < 28) {
      const void* src; int w; int f2;
      if (tid < 16)      { src = cov;  w = 16; f2 = tid; }
      else if (tid < 24) { src = trh;  w = 8;  f2 = tid - 16; }
      else               { src = outh; w = 4;  f2 = tid - 24; }
      float s1 = 0.f, s2 = 0.f;
      for (int t = 0; t < NLH; ++t) {
        const float v = ldv(src, (row*NLH + t)*w + f2, bf);
        s1 += v; s2 += v*v;
      }
      const float m = s1 / NLH;
      const float var = s2 / NLH - m*m;
      sm_[tid] = m;
      ss_[tid] = sqrtf(fmaxf(var, 0.f)) + EPS;
    }
    __syncthreads();
    for (int e = tid; e < NLH*28; e += 384) {
      const int t = e / 28, f2 = e % 28;
      const void* src; int w; int ff;
      if (f2 < 16)      { src = cov;  w = 16; ff = f2; }
      else if (f2 < 24) { src = trh;  w = 8;  ff = f2 - 16; }
      else              { src = outh; w = 4;  ff = f2 - 24; }
      const float v = ldv(src, (row*NLH + t)*w + ff, bf);
      xs[e] = (v - sm_[f2]) / ss_[f2];
    }
    __syncthreads();
    float* hout = ws + WSH_OFF + (row*4 + back)*128;
    if (back == 0) gru_run<28, NLH>(xs, 0, eWf, eUf, ebf, ecf, bf, hout, h0, h1, rz);
    else           gru_run<28, NLH>(xs, 1, eWb, eUb, ebb, ecb, bf, hout, h0, h1, rz);
  } else {          // ---- decoder ----
    const int b2 = bid - 256;
    const int row = b2 >> 1, back = b2 & 1;
    if (tid < 8) {
      float s1 = 0.f, s2 = 0.f;
      for (int t = 0; t < NLH; ++t) {
        const float v = ldv(trh, (row*NLH + t)*8 + tid, bf);
        s1 += v; s2 += v*v;
      }
      const float m = s1 / NLH;
      const float var = s2 / NLH - m*m;
      sm_[tid] = m;
      ss_[tid] = sqrtf(fmaxf(var, 0.f)) + EPS;
    }
    __syncthreads();
    for (int e = tid; e < NLP*8; e += 384) {
      const int t = e >> 3, f2 = e & 7;
      const float v = ldv(trt, (row*NLP + t)*8 + f2, bf);
      xs[e] = (v - sm_[f2]) / ss_[f2];
    }
    __syncthreads();
    float* hout = ws + WSH_OFF + (row*4 + 2 + back)*128;
    if (back == 0) gru_run<8, NLP>(xs, 0, dWf, dUf, dbf, dcf, bf, hout, h0, h1, rz);
    else           gru_run<8, NLP>(xs, 1, dWb, dUb, dbb, dcb, bf, hout, h0, h1, rz);
  }
}

// ---------------------------------------------------------------------------
// SDE: one layer for a 4-row half. FOLD=1 applies the previous layer's LN
// affine analytically: pre = rs*(P - m*Swg) + (b + Swb).
// ---------------------------------------------------------------------------
template<int K, int NC, int KSPLIT, int KPC, int FOLD>
__device__ __forceinline__ void mlp(
    const float* in,          // LDS, 4 rows, stride K (raw tanh if FOLD)
    const float* w,           // per-thread regs: 2 cols x KPC (g-folded if FOLD)
    const float* btot,        // LDS [NC] slice: bias (+ Sum(w*be) if FOLD)
    const float* Swg,         // LDS [NC] slice (FOLD only)
    const float* mrow, const float* rsrow,   // per-row LN stats of `in`
    float* scr, float* tsl,
    u64t* actG, u64t* psG, int colg)
{
  const int tid = threadIdx.x;
  const int cp = tid % (NC/2);
  const int kc = tid / (NC/2);
  const int kk = kc * KPC;
  float p0[4], p1[4];
  #pragma unroll
  for (int r = 0; r < 4; ++r) { p0[r] = 0.f; p1[r] = 0.f; }
  #pragma unroll
  for (int i = 0; i < KPC; i += 4) {
    const float wa0 = w[i],     wa1 = w[i+1],     wa2 = w[i+2],     wa3 = w[i+3];
    const float wb0 = w[KPC+i], wb1 = w[KPC+i+1], wb2 = w[KPC+i+2], wb3 = w[KPC+i+3];
    #pragma unroll
    for (int r = 0; r < 4; ++r) {
      const float4 av = *(const float4*)(in + r*K + kk + i);
      p0[r] += wa0*av.x + wa1*av.y + wa2*av.z + wa3*av.w;
      p1[r] += wb0*av.x + wb1*av.y + wb2*av.z + wb3*av.w;
    }
  }
  #pragma unroll
  for (int r = 0; r < 4; ++r) {            // stride-5 pad reduce scratch
    scr[(kc*NC + 2*cp + 0)*5 + r] = p0[r];
    scr[(kc*NC + 2*cp + 1)*5 + r] = p1[r];
  }
  __syncthreads();
  if (tid < 4*(NC/2)) {                    // one row, 2 adjacent cols / thread
    const int r = tid / (NC/2), c2 = tid % (NC/2);
    float P0 = 0.f, P1 = 0.f;
    #pragma unroll
    for (int q = 0; q < KSPLIT; ++q) {
      P0 += scr[(q*NC + 2*c2 + 0)*5 + r];
      P1 += scr[(q*NC + 2*c2 + 1)*5 + r];
    }
    float v0, v1;
    if (FOLD) {
      const float m = mrow[r], rs = rsrow[r];
      v0 = rs*(P0 - m*Swg[2*c2 + 0]) + btot[2*c2 + 0];
      v1 = rs*(P1 - m*Swg[2*c2 + 1]) + btot[2*c2 + 1];
    } else {
      v0 = P0 + btot[2*c2 + 0];
      v1 = P1 + btot[2*c2 + 1];
    }
    const float t0 = tanhf(v0), t1 = tanhf(v1);
    tsl[r*NC + 2*c2 + 0] = t0;
    tsl[r*NC + 2*c2 + 1] = t1;
    g_st64(&actG[r*(NC*8) + colg*(NC/2) + c2], pk2(t0, t1));
  }
  __syncthreads();
  if (tid < 4) {                            // packed raw-tanh LN partials
    float s1 = 0.f, s2 = 0.f;
    #pragma unroll
    for (int cl = 0; cl < NC; ++cl) { const float v = tsl[tid*NC + cl]; s1 += v; s2 += v*v; }
    g_st64(&psG[colg*4 + tid], pk2(s1, s2));
  }
}

// Pull raw tanh values + partials; compute per-row m/rs. No normalize pass.
template<int NCT>
__device__ __forceinline__ void consume(
    float* act, const u64t* actG, const u64t* psG,
    float* psL, float* mrow, float* rsrow)
{
  const int tid = threadIdx.x;
  for (int e = tid; e < 2*NCT; e += 256) {   // 4 rows x NCT cols / 2 per u64
    U64 t; t.u = g_ld64(actG + e);
    act[2*e + 0] = t.f[0];
    act[2*e + 1] = t.f[1];
  }
  if (tid < 64) {
    U64 t; t.u = g_ld64(psG + tid);
    psL[2*tid + 0] = t.f[0];
    psL[2*tid + 1] = t.f[1];
  }
  __syncthreads();
  if (tid < 4) {
    float s1 = 0.f, s2 = 0.f;
    #pragma unroll
    for (int cg = 0; cg < 16; ++cg) {
      s1 += psL[(cg*4 + tid)*2 + 0];
      s2 += psL[(cg*4 + tid)*2 + 1];
    }
    const float m = s1 / (float)NCT;
    const float var = s2 / (float)NCT - m*m;
    mrow[tid] = m;
    rsrow[tid] = rsqrtf(var + EPS);
  }
  __syncthreads();
}

__global__ __launch_bounds__(256)
void k_sde(float* ws,
           const void* W0, const void* b0, const void* g0, const void* be0,
           const void* W1, const void* b1, const void* g1, const void* be1,
           const void* W2, const void* b2, const void* g2, const void* be2,
           const void* noise, const void* lnvw)
{
  __shared__ __align__(16) float st[8*256];
  __shared__ __align__(16) float act0[4*512];
  __shared__ __align__(16) float act1[4*512];
  __shared__ __align__(16) float scr[2560];
  __shared__ float scrE[256];
  __shared__ float tsl[128], psL[128];
  __shared__ float mrow[4], rsrow[4], lacc[8];
  __shared__ float bAs[32], btotB[32], SwgB[32], btotC[16], SwgC[16];
  __shared__ float gC[256], beC[256];

  const bool bf = (((const unsigned*)lnvw)[0] != 0x3F800000u);
  const int tid  = threadIdx.x;
  const int bid  = blockIdx.x;
  const int rp   = bid & 15;          // rowg-pair; cohort shares bid%16 -> bid%8
  const int colg = bid >> 4;
  const int rg0  = rp*2, rg1 = rp*2 + 1;

  gC[tid] = ldv(g2, tid, bf); beC[tid] = ldv(be2, tid, bf);

  // ---- weights: load + fold LN affine ----
  float w0r[32], w1r[64], w2r[32];
  const int cp = tid % 16, kc = tid / 16;     // A,B decomposition
  const int cp2 = tid % 8, kc2 = tid / 8;     // C decomposition
  float sg1[2] = {0.f, 0.f}, sb1[2] = {0.f, 0.f};
  float sg2[2] = {0.f, 0.f}, sb2[2] = {0.f, 0.f};
  #pragma unroll
  for (int cc = 0; cc < 2; ++cc)
    #pragma unroll
    for (int i = 0; i < 16; ++i)
      w0r[cc*16 + i] = ldv(W0, (colg*32 + 2*cp + cc)*256 + kc*16 + i, bf);
  #pragma unroll
  for (int cc = 0; cc < 2; ++cc)
    #pragma unroll
    for (int i = 0; i < 32; ++i) {
      const int k = kc*32 + i;
      const float wv = ldv(W1, (colg*32 + 2*cp + cc)*512 + k, bf);
      const float gv = ldv(g0, k, bf), bev = ldv(be0, k, bf);
      w1r[cc*32 + i] = wv*gv;
      sg1[cc] += wv*gv; sb1[cc] += wv*bev;
    }
  #pragma unroll
  for (int cc = 0; cc < 2; ++cc)
    #pragma unroll
    for (int i = 0; i < 16; ++i) {
      const int k = kc2*16 + i;
      const float wv = ldv(W2, (colg*16 + 2*cp2 + cc)*512 + k, bf);
      const float gv = ldv(g1, k, bf), bev = ldv(be1, k, bf);
      w2r[cc*16 + i] = wv*gv;
      sg2[cc] += wv*gv; sb2[cc] += wv*bev;
    }
  // reduce fold constants (per this colg's column slice)
  scr[kc*32 + 2*cp + 0] = sg1[0]; scr[kc*32 + 2*cp + 1] = sg1[1];
  scr[512 + kc*32 + 2*cp + 0] = sb1[0]; scr[512 + kc*32 + 2*cp + 1] = sb1[1];
  __syncthreads();
  if (tid < 32) {
    float a = 0.f, b = 0.f;
    #pragma unroll
    for (int q = 0; q < 16; ++q) { a += scr[q*32 + tid]; b += scr[512 + q*32 + tid]; }
    SwgB[tid] = a;
    btotB[tid] = ldv(b1, colg*32 + tid, bf) + b;
    bAs[tid]  = ldv(b0, colg*32 + tid, bf);
  }
  __syncthreads();
  scr[kc2*16 + 2*cp2 + 0] = sg2[0]; scr[kc2*16 + 2*cp2 + 1] = sg2[1];
  scr[512 + kc2*16 + 2*cp2 + 0] = sb2[0]; scr[512 + kc2*16 + 2*cp2 + 1] = sb2[1];
  __syncthreads();
  if (tid < 16) {
    float a = 0.f, b = 0.f;
    #pragma unroll
    for (int q = 0; q < 32; ++q) { a += scr[q*16 + tid]; b += scr[512 + q*16 + tid]; }
    SwgC[tid] = a;
    btotC[tid] = ldv(b2, colg*16 + tid, bf) + b;
  }

  // x0 = [0.5*(enc_f+enc_b), 0.5*(dec_f+dec_b)] for this WG's 8 rows.
  const float* wsh = ws + WSH_OFF;
  for (int e = tid; e < 8*256; e += 256) {
    const int r8 = e >> 8, d = e & 255;
    const int row = rp*8 + r8;
    float v;
    if (d < 128) v = 0.5f*(wsh[(row*4 + 0)*128 + d]         + wsh[(row*4 + 1)*128 + d]);
    else         v = 0.5f*(wsh[(row*4 + 2)*128 + (d - 128)] + wsh[(row*4 + 3)*128 + (d - 128)]);
    st[e] = v;
  }
  if (tid < 8) lacc[tid] = 0.f;
  __syncthreads();
  float* ysw = ws + YS_OFF;
  if (colg == 0) {  // sample 0 = aug0
    for (int e = tid; e < 8*257; e += 256) {
      const int rr = e / 257, d = e % 257;
      ysw[((rp*8 + rr)*8 + 0)*257 + d] = (d < 256) ? st[rr*256 + d] : 0.f;
    }
  }

  u64t* aA0 = (u64t*)(ws + ACTA_OFF) + rg0*1024;
  u64t* aA1 = (u64t*)(ws + ACTA_OFF) + rg1*1024;
  u64t* aB0 = (u64t*)(ws + ACTB_OFF) + rg0*1024;
  u64t* aB1 = (u64t*)(ws + ACTB_OFF) + rg1*1024;
  u64t* aC0 = (u64t*)(ws + ACTC_OFF) + rg0*512;
  u64t* aC1 = (u64t*)(ws + ACTC_OFF) + rg1*512;
  u64t* pA0 = (u64t*)(ws + PSA_OFF) + rg0*64;
  u64t* pA1 = (u64t*)(ws + PSA_OFF) + rg1*64;
  u64t* pB0 = (u64t*)(ws + PSB_OFF) + rg0*64;
  u64t* pB1 = (u64t*)(ws + PSB_OFF) + rg1*64;
  u64t* pC0 = (u64t*)(ws + PSC_OFF) + rg0*64;
  u64t* pC1 = (u64t*)(ws + PSC_OFF) + rg1*64;
  unsigned* cnt = (unsigned*)(ws + CNT_OFF);
  unsigned* c00 = &cnt[(rg0*3 + 0)*16]; unsigned* c01 = &cnt[(rg1*3 + 0)*16];
  unsigned* c10 = &cnt[(rg0*3 + 1)*16]; unsigned* c11 = &cnt[(rg1*3 + 1)*16];
  unsigned* c20 = &cnt[(rg0*3 + 2)*16]; unsigned* c21 = &cnt[(rg1*3 + 2)*16];

  const int r8 = tid >> 5, d0 = (tid & 31)*8;

  #pragma unroll 1
  for (int s = 0; s < NSTEP; ++s) {
    const unsigned t16 = 16u*(unsigned)(s + 1);

    // Prefetch this step's noise (8 rows across 256 threads).
    const int nb = ((s*NB) + rp*8 + r8)*256 + d0;
    uint4 nzb; float4 nf0, nf1;
    if (bf) nzb = *(const uint4*)((const unsigned short*)noise + nb);
    else { nf0 = *(const float4*)((const float*)noise + nb);
           nf1 = *(const float4*)((const float*)noise + nb + 4); }

    // ---- layer 0, both halves ----
    mlp<256,32,16,16,0>(st,        w0r, bAs, nullptr, mrow, rsrow, scr, tsl, aA0, pA0, colg);
    bar_arrive(c00);
    mlp<256,32,16,16,0>(st + 1024, w0r, bAs, nullptr, mrow, rsrow, scr, tsl, aA1, pA1, colg);
    bar_arrive(c01);

    // ---- layer 1 ----
    bar_wait(c00, t16);
    consume<512>(act0, aA0, pA0, psL, mrow, rsrow);
    mlp<512,32,16,32,1>(act0, w1r, btotB, SwgB, mrow, rsrow, scr, tsl, aB0, pB0, colg);
    bar_arrive(c10);
    bar_wait(c01, t16);
    consume<512>(act1, aA1, pA1, psL, mrow, rsrow);
    mlp<512,32,16,32,1>(act1, w1r, btotB, SwgB, mrow, rsrow, scr, tsl, aB1, pB1, colg);
    bar_arrive(c11);

    // ---- layer 2 ----
    bar_wait(c10, t16);
    consume<512>(act0, aB0, pB0, psL, mrow, rsrow);
    mlp<512,16,32,16,1>(act0, w2r, btotC, SwgC, mrow, rsrow, scr, tsl, aC0, pC0, colg);
    bar_arrive(c20);
    bar_wait(c11, t16);
    consume<512>(act1, aB1, pB1, psL, mrow, rsrow);
    mlp<512,16,32,16,1>(act1, w2r, btotC, SwgC, mrow, rsrow, scr, tsl, aC1, pC1, colg);
    bar_arrive(c21);

    // ---- Euler + flq (LN-C affine applied inline) ----
    bar_wait(c20, t16);
    consume<256>(act0, aC0, pC0, psL, mrow, rsrow);
    if (tid < 128) {
      float nz[8];
      if (bf) { up2(nzb.x,&nz[0]); up2(nzb.y,&nz[2]); up2(nzb.z,&nz[4]); up2(nzb.w,&nz[6]); }
      else { nz[0]=nf0.x; nz[1]=nf0.y; nz[2]=nf0.z; nz[3]=nf0.w;
             nz[4]=nf1.x; nz[5]=nf1.y; nz[6]=nf1.z; nz[7]=nf1.w; }
      const float m = mrow[r8], rs = rsrow[r8];
      float u2 = 0.f;
      #pragma unroll
      for (int q = 0; q < 8; ++q) {
        const int d = d0 + q;
        const float f  = (act0[r8*256 + d] - m)*rs*gC[d] + beC[d];
        const float ys = st[r8*256 + d];
        const float uu = f + ys;                 // u = 2*(f+ys); scale later
        u2 += uu*uu;
        st[r8*256 + d] = ys + f*DT_ + SIG_*SQDT_*nz[q];
      }
      scrE[tid] = u2;
    }
    bar_wait(c21, t16);
    consume<256>(act1, aC1, pC1, psL, mrow, rsrow);
    if (tid >= 128) {
      float nz[8];
      if (bf) { up2(nzb.x,&nz[0]); up2(nzb.y,&nz[2]); up2(nzb.z,&nz[4]); up2(nzb.w,&nz[6]); }
      else { nz[0]=nf0.x; nz[1]=nf0.y; nz[2]=nf0.z; nz[3]=nf0.w;
             nz[4]=nf1.x; nz[5]=nf1.y; nz[6]=nf1.z; nz[7]=nf1.w; }
      const int rl = r8 - 4;
      const float m = mrow[rl], rs = rsrow[rl];
      float u2 = 0.f;
      #pragma unroll
      for (int q = 0; q < 8; ++q) {
        const int d = d0 + q;
        const float f  = (act1[rl*256 + d] - m)*rs*gC[d] + beC[d];
        const float ys = st[r8*256 + d];
        const float uu = f + ys;
        u2 += uu*uu;
        st[r8*256 + d] = ys + f*DT_ + SIG_*SQDT_*nz[q];
      }
      scrE[tid] = u2;
    }
    __syncthreads();
    if (tid < 8) {
      float tot = 0.f;
      #pragma unroll
      for (int c = 0; c < 32; ++c) tot += scrE[tid*32 + c];
      lacc[tid] += 2.f*tot*DT_;                  // flq*DT = 0.5*sum((2u)^2)*DT
    }
    __syncthreads();
    if (((s + 1) % NSUB) == 0 && colg == 0) {
      const int smp = (s + 1)/NSUB;
      for (int e = tid; e < 8*257; e += 256) {
        const int rr = e / 257, d = e % 257;
        ysw[((rp*8 + rr)*8 + smp)*257 + d] = (d < 256) ? st[rr*256 + d] : lacc[rr];
      }
      __syncthreads();
    }
  }
}

// ---------------------------------------------------------------------------
// Epilogue: decoder head + output packing (mu | var | logqp)
// ---------------------------------------------------------------------------
__global__ __launch_bounds__(128)
void k_epi(const float* ws, const void* outh,
           const void* outW, const void* outB,
           const void* lvw, const void* lvb,
           void* d_out)
{
  __shared__ __align__(16) float ysl[8*257];
  __shared__ __align__(16) float ow[8*128];
  __shared__ float dout[64];
  __shared__ float om4[4], os4[4], vmv[4], vrs[4], ob[8], lw[4], lb[4];
  const bool bf = (((const unsigned*)lvw)[0] != 0x3F800000u);
  const int row = blockIdx.x, tid = threadIdx.x;
  const float* ysw = ws + YS_OFF + row*(8*257);
  for (int e = tid; e < 8*257; e += 128) ysl[e] = ysw[e];
  for (int e = tid; e < 1024; e += 128)  ow[e]  = ldv(outW, e, bf);
  if (tid < 8) ob[tid] = ldv(outB, tid, bf);
  if (tid < 4) { lw[tid] = ldv(lvw, tid, bf); lb[tid] = ldv(lvb, tid, bf); }
  if (tid < 4) {  // om / os_ from outcome_history
    float s1 = 0.f, s2 = 0.f;
    for (int t = 0; t < NLH; ++t) {
      const float v = ldv(outh, (row*NLH + t)*4 + tid, bf);
      s1 += v; s2 += v*v;
    }
    const float m = s1 / NLH;
    const float var = s2 / NLH - m*m;
    om4[tid] = m;
    os4[tid] = sqrtf(fmaxf(var, 0.f)) + EPS;   // already includes +EPS
  }
  __syncthreads();
  if (tid < 64) {
    const int smp = tid >> 3, o = tid & 7;
    float a = ob[o];
    #pragma unroll
    for (int k = 0; k < 128; ++k) a += ysl[smp*257 + k]*ow[o*128 + k];
    dout[smp*8 + o] = a;
  }
  __syncthreads();
  if (tid < 4) {  // var_o mean/var over the 8 samples
    float s1 = 0.f, s2 = 0.f;
    #pragma unroll
    for (int smp = 0; smp < 8; ++smp) { const float v = dout[smp*8 + 4 + tid]; s1 += v; s2 += v*v; }
    const float m = s1 / 8.f;
    const float var = s2 / 8.f - m*m;
    vmv[tid] = m;
    vrs[tid] = rsqrtf(var + EPS);
  }
  __syncthreads();
  if (tid < 32) {
    const int smp = tid >> 2, j = tid & 3;
    const float mu = dout[smp*8 + j]*os4[j] + om4[j];
    st_out(d_out, (row*8 + smp)*4 + j, mu, bf);
    const float vo = dout[smp*8 + 4 + j];
    const float vr = sigm((vo - vmv[j])*vrs[j]*lw[j] + lb[j]);
    st_out(d_out, 4096 + (row*8 + smp)*4 + j, vr, bf);
  }
  for (int e = tid; e < 129*8; e += 128) {
    const int j = e >> 3, smp = e & 7;
    st_out(d_out, 8192 + (row*129 + j)*8 + smp, ysl[smp*257 + 128 + j], bf);
  }
}

// ---------------------------------------------------------------------------
extern "C" void kernel_launch(void* const* d_in, const int* in_sizes, int n_in,
                              void* d_out, int out_size, void* d_ws, size_t ws_size,
                              hipStream_t stream) {
  (void)in_sizes; (void)n_in; (void)out_size; (void)ws_size;
  float* ws = (float*)d_ws;
  const void* lnvw = d_in[35];

  k_gru<<<512, 384, 0, stream>>>(
      d_in[0], d_in[1], d_in[2], d_in[3],
      d_in[5], d_in[6], d_in[7], d_in[8],
      d_in[9], d_in[10], d_in[11], d_in[12],
      d_in[13], d_in[14], d_in[15], d_in[16],
      d_in[17], d_in[18], d_in[19], d_in[20],
      ws, lnvw);
  k_sde<<<256, 256, 0, stream>>>(
      ws,
      d_in[21], d_in[22], d_in[23], d_in[24],
      d_in[25], d_in[26], d_in[27], d_in[28],
      d_in[29], d_in[30], d_in[31], d_in[32],
      d_in[37], lnvw);
  k_epi<<<128, 128, 0, stream>>>(
      (const float*)d_ws, d_in[2],
      d_in[33], d_in[34], d_in[35], d_in[36],
      d_out);
}